// Round 5
// baseline (377.111 us; speedup 1.0000x reference)
//
#include <hip/hip_runtime.h>
#include <hip/hip_bf16.h>

typedef __attribute__((ext_vector_type(8))) short short8;
typedef __attribute__((ext_vector_type(4))) float floatx4;
typedef unsigned short u16;

#define D 256
#define BM 128
#define NT 512
#define GRID 1024

__device__ __forceinline__ short f2bf(float f) {
    return __builtin_bit_cast(short, __float2bfloat16(f));
}

// prep: blocks [0,256): W1 fp32 [k][n] -> W1F bf16 MFMA-fragment-major;
//       blocks [256,384): zero d_out.
__global__ void prep_kernel(const float* __restrict__ W1, u16* __restrict__ W1F,
                            float* __restrict__ out, int outn) {
    const int b = blockIdx.x;
    if (b < D) {
        const int k = b, n = threadIdx.x;
        const int k0t = k >> 5, g = (k >> 3) & 3, j = k & 7;
        const int nt = n >> 4, l15 = n & 15;
        W1F[(long)((((k0t << 4) + nt) << 6) + (g << 4) + l15) * 8 + j] = (u16)f2bf(W1[k * D + n]);
    } else {
        int i = (b - D) * 256 + threadIdx.x;
        const int stride = (gridDim.x - D) * 256;
        for (; i < outn; i += stride) out[i] = 0.f;
    }
}

#define GLOAD_LDS(g, l) __builtin_amdgcn_global_load_lds( \
    (const __attribute__((address_space(1))) unsigned int*)(g), \
    (__attribute__((address_space(3))) unsigned int*)(l), 16, 0, 0)

// Persistent pipelined head: grid-stride over 128-row tiles, K split in two
// 128-float halves, double-buffered fp32 LDS filled by global_load_lds with
// source-side XOR swizzle (LDS[r][c] = G[r][c ^ (r&7)], 16B chunks).
__launch_bounds__(NT, 2)
__global__ void head_kernel(const float* __restrict__ forces,
                            const float* __restrict__ V_st,
                            const u16*   __restrict__ W1F,
                            const float* __restrict__ b1,
                            const float* __restrict__ W2,
                            const float* __restrict__ b2,
                            const int*   __restrict__ idx_t,
                            float* __restrict__ out,
                            int E) {
    __shared__ float Abuf[2][BM * 128];   // 2 x 64 KiB fp32 K-half buffers
    __shared__ float s_red[4][BM];        // 2 KiB cross-wave scalar reduce

    const int tid  = threadIdx.x;
    const int lane = tid & 63;
    const int w    = tid >> 6;            // 0..7
    const int wm   = w >> 2;              // row half 0..1
    const int wn   = w & 3;               // col quarter 0..3
    const int l15  = lane & 15;
    const int g    = lane >> 4;           // 0..3
    const int q    = l15 & 7;             // read-side swizzle key (row&7 == l15&7)

    const int ntiles = (E + BM - 1) / BM;

    // staging geometry: wave w stages LDS rows [w*16, w*16+16); inst j covers rows 2j,2j+1
    const int ldsrow0 = w * 16;
    const int lsub    = lane >> 5;        // 0/1: row within the pair
    const int c31     = lane & 31;        // 16B chunk within 512B half-row

    // issue 8 global_load_lds (1 KB each) for tile/kh into Abuf[buf]
    auto STAGE = [&](int buf, long tile, int kh) {
#pragma unroll
        for (int j = 0; j < 8; ++j) {
            long rowg = tile * BM + ldsrow0 + 2 * j + lsub;
            if (rowg > (long)E - 1) rowg = (long)E - 1;   // never taken for E%128==0
            const float* src = forces + rowg * D + kh * 128
                             + ((c31 ^ ((int)rowg & 7)) << 2);
            GLOAD_LDS(src, &Abuf[buf][(ldsrow0 + 2 * j) * 128]);
        }
    };

    floatx4 acc[4][4];
#pragma unroll
    for (int mr = 0; mr < 4; ++mr)
#pragma unroll
        for (int nc = 0; nc < 4; ++nc)
            acc[mr][nc] = (floatx4){0.f, 0.f, 0.f, 0.f};

    // per-lane epilogue constants
    float b1v[4], w2v[4];
#pragma unroll
    for (int nc = 0; nc < 4; ++nc) {
        int n = wn * 64 + nc * 16 + l15;
        b1v[nc] = b1[n];
        w2v[nc] = W2[n];
    }
    const float b2v = b2[0];

    // one K-half (4 k-steps of 32) from Abuf[buf]; kh selects global k0t base
    auto COMPUTE = [&](int buf, int kh) {
#pragma unroll
        for (int kl = 0; kl < 4; ++kl) {
            const int k0t = kh * 4 + kl;
            short8 bfr[4];
#pragma unroll
            for (int nc = 0; nc < 4; ++nc) {
                int nt = wn * 4 + nc;
                bfr[nc] = *(const short8*)(W1F + (long)((k0t * 16 + nt) * 64 + lane) * 8);
            }
            const int cg = kl * 8 + 2 * g;   // 16B chunk of k-local g*8..g*8+3
            short8 af[4];
#pragma unroll
            for (int mr = 0; mr < 4; ++mr) {
                int row = wm * 64 + mr * 16 + l15;
                floatx4 f0 = *(const floatx4*)&Abuf[buf][row * 128 + ((cg ^ q) << 2)];
                floatx4 f1 = *(const floatx4*)&Abuf[buf][row * 128 + (((cg + 1) ^ q) << 2)];
                short8 a;
#pragma unroll
                for (int jj = 0; jj < 4; ++jj) { a[jj] = f2bf(f0[jj]); a[4 + jj] = f2bf(f1[jj]); }
                af[mr] = a;
            }
#pragma unroll
            for (int mr = 0; mr < 4; ++mr)
#pragma unroll
                for (int nc = 0; nc < 4; ++nc)
                    acc[mr][nc] = __builtin_amdgcn_mfma_f32_16x16x32_bf16(
                        af[mr], bfr[nc], acc[mr][nc], 0, 0, 0);
        }
    };

    long t = blockIdx.x;
    if (t < (long)ntiles) STAGE(0, t, 0);
    __syncthreads();   // drain H0 (compiler emits vmcnt(0) before s_barrier)

    for (; t < (long)ntiles; ) {
        STAGE(1, t, 1);          // prefetch K-half 1 of this tile
        COMPUTE(0, 0);
        __syncthreads();         // buf1 ready

        const long tn = t + GRID;
        if (tn < (long)ntiles) STAGE(0, tn, 0);   // prefetch next tile's K-half 0
        COMPUTE(1, 1);

        // ---- epilogue: silu(z+b1) dot W2 over this wave's 64 cols ----
        float part[4][4];
#pragma unroll
        for (int mr = 0; mr < 4; ++mr)
#pragma unroll
            for (int r = 0; r < 4; ++r) {
                float s = 0.f;
#pragma unroll
                for (int nc = 0; nc < 4; ++nc) {
                    float z = acc[mr][nc][r] + b1v[nc];
                    float h = z / (1.f + __expf(-z));
                    s += h * w2v[nc];
                }
                part[mr][r] = s;
            }
        // re-zero acc for next tile
#pragma unroll
        for (int mr = 0; mr < 4; ++mr)
#pragma unroll
            for (int nc = 0; nc < 4; ++nc)
                acc[mr][nc] = (floatx4){0.f, 0.f, 0.f, 0.f};

#pragma unroll
        for (int off = 1; off < 16; off <<= 1)
#pragma unroll
            for (int mr = 0; mr < 4; ++mr)
#pragma unroll
                for (int r = 0; r < 4; ++r)
                    part[mr][r] += __shfl_xor(part[mr][r], off, 16);

        if (l15 == 0) {
#pragma unroll
            for (int mr = 0; mr < 4; ++mr)
#pragma unroll
                for (int r = 0; r < 4; ++r)
                    s_red[wn][wm * 64 + mr * 16 + g * 4 + r] = part[mr][r];
        }
        __syncthreads();         // s_red visible; also drains prefetch H0(tn)

        if (tid < BM) {
            long e = t * BM + tid;
            if (e < E) {
                float s = s_red[0][tid] + s_red[1][tid] + s_red[2][tid] + s_red[3][tid] + b2v;
                float vx = V_st[e * 3 + 0], vy = V_st[e * 3 + 1], vz = V_st[e * 3 + 2];
                long node = (long)idx_t[e];
                atomicAdd(&out[node * 3 + 0], s * vx);
                atomicAdd(&out[node * 3 + 1], s * vy);
                atomicAdd(&out[node * 3 + 2], s * vz);
            }
        }
        t = tn;
        // next iteration's first __syncthreads separates these s_red reads
        // from the next tile's s_red writes
    }
}

extern "C" void kernel_launch(void* const* d_in, const int* in_sizes, int n_in,
                              void* d_out, int out_size, void* d_ws, size_t ws_size,
                              hipStream_t stream) {
    const float* forces = (const float*)d_in[0];
    const float* V_st   = (const float*)d_in[1];
    const float* W1     = (const float*)d_in[2];
    const float* b1     = (const float*)d_in[3];
    const float* W2     = (const float*)d_in[4];
    const float* b2     = (const float*)d_in[5];
    const int*   idx    = (const int*)d_in[6];
    const int E = in_sizes[6];

    u16* W1F = (u16*)d_ws;  // 256*256*2 = 131072 B

    prep_kernel<<<D + 128, 256, 0, stream>>>(W1, W1F, (float*)d_out, out_size);
    head_kernel<<<GRID, NT, 0, stream>>>(forces, V_st, W1F, b1, W2, b2, idx,
                                         (float*)d_out, E);
}

// Round 6
// 363.657 us; speedup vs baseline: 1.0370x; 1.0370x over previous
//
#include <hip/hip_runtime.h>
#include <hip/hip_bf16.h>

typedef __attribute__((ext_vector_type(8))) short short8;
typedef __attribute__((ext_vector_type(4))) float floatx4;
typedef unsigned short u16;

#define D 256
#define BM 128
#define NT 512
#define GRID 1024

__device__ __forceinline__ short f2bf(float f) {
    return __builtin_bit_cast(short, __float2bfloat16(f));
}

// prep: blocks [0,256): W1 fp32 [k][n] -> W1F bf16 MFMA-fragment-major;
//       blocks [256,384): zero d_out.
__global__ void prep_kernel(const float* __restrict__ W1, u16* __restrict__ W1F,
                            float* __restrict__ out, int outn) {
    const int b = blockIdx.x;
    if (b < D) {
        const int k = b, n = threadIdx.x;
        const int k0t = k >> 5, g = (k >> 3) & 3, j = k & 7;
        const int nt = n >> 4, l15 = n & 15;
        W1F[(long)((((k0t << 4) + nt) << 6) + (g << 4) + l15) * 8 + j] = (u16)f2bf(W1[k * D + n]);
    } else {
        int i = (b - D) * 256 + threadIdx.x;
        const int stride = (gridDim.x - D) * 256;
        for (; i < outn; i += stride) out[i] = 0.f;
    }
}

#define GLOAD_LDS(g, l) __builtin_amdgcn_global_load_lds( \
    (const __attribute__((address_space(1))) unsigned int*)(g), \
    (__attribute__((address_space(3))) unsigned int*)(l), 16, 0, 0)

// One K-half (4 k-steps of 32) from fp32 LDS buffer Ab; B-fragments entirely
// in registers (static indices via template KH) -> NO vmem in the compute path.
template<int KH>
__device__ __forceinline__ void compute_half(const float* Ab, const short8 (&bfr)[32],
                                             floatx4 (&acc)[4][4],
                                             int wm, int g, int l15, int q) {
#pragma unroll
    for (int kl = 0; kl < 4; ++kl) {
        const int k0t = KH * 4 + kl;
        const int cg  = kl * 8 + 2 * g;   // 16B chunk of local k
        short8 af[4];
#pragma unroll
        for (int mr = 0; mr < 4; ++mr) {
            int row = wm * 64 + mr * 16 + l15;
            floatx4 f0 = *(const floatx4*)&Ab[row * 128 + ((cg ^ q) << 2)];
            floatx4 f1 = *(const floatx4*)&Ab[row * 128 + (((cg + 1) ^ q) << 2)];
            short8 a;
#pragma unroll
            for (int jj = 0; jj < 4; ++jj) { a[jj] = f2bf(f0[jj]); a[4 + jj] = f2bf(f1[jj]); }
            af[mr] = a;
        }
#pragma unroll
        for (int mr = 0; mr < 4; ++mr)
#pragma unroll
            for (int nc = 0; nc < 4; ++nc)
                acc[mr][nc] = __builtin_amdgcn_mfma_f32_16x16x32_bf16(
                    af[mr], bfr[k0t * 4 + nc], acc[mr][nc], 0, 0, 0);
    }
}

// Persistent pipelined head: grid-stride over 128-row tiles, K split in two
// 128-float halves, double-buffered fp32 LDS filled by global_load_lds with
// source-side XOR swizzle (LDS[r][c] = G[r][c ^ (r&7)], 16B chunks).
__launch_bounds__(NT, 2)
__global__ void head_kernel(const float* __restrict__ forces,
                            const float* __restrict__ V_st,
                            const u16*   __restrict__ W1F,
                            const float* __restrict__ b1,
                            const float* __restrict__ W2,
                            const float* __restrict__ b2,
                            const int*   __restrict__ idx_t,
                            float* __restrict__ out,
                            int E) {
    __shared__ float Abuf[2][BM * 128];   // 2 x 64 KiB fp32 K-half buffers
    __shared__ float s_red[4][BM];        // 2 KiB cross-wave scalar reduce

    const int tid  = threadIdx.x;
    const int lane = tid & 63;
    const int w    = tid >> 6;            // 0..7
    const int wm   = w >> 2;              // row half 0..1
    const int wn   = w & 3;               // col quarter 0..3
    const int l15  = lane & 15;
    const int g    = lane >> 4;           // 0..3
    const int q    = l15 & 7;             // read-side swizzle key (row&7 == l15&7)

    const int ntiles = (E + BM - 1) / BM;

    // staging geometry: wave w stages LDS rows [w*16, w*16+16); inst j covers rows 2j,2j+1
    const int ldsrow0 = w * 16;
    const int lsub    = lane >> 5;        // 0/1: row within the pair
    const int c31     = lane & 31;        // 16B chunk within 512B half-row

    auto STAGE = [&](int buf, long tile, int kh) {
#pragma unroll
        for (int j = 0; j < 8; ++j) {
            long rowg = tile * BM + ldsrow0 + 2 * j + lsub;
            if (rowg > (long)E - 1) rowg = (long)E - 1;   // never taken for E%128==0
            const float* src = forces + rowg * D + kh * 128
                             + ((c31 ^ ((int)rowg & 7)) << 2);
            GLOAD_LDS(src, &Abuf[buf][(ldsrow0 + 2 * j) * 128]);
        }
    };

    // ---- prologue: hoist ALL B-fragments into registers (tile-invariant) ----
    short8 bfr[32];
#pragma unroll
    for (int k0t = 0; k0t < 8; ++k0t)
#pragma unroll
        for (int nc = 0; nc < 4; ++nc)
            bfr[k0t * 4 + nc] =
                *(const short8*)(W1F + (long)((k0t * 16 + wn * 4 + nc) * 64 + lane) * 8);

    float b1v[4], w2v[4];
#pragma unroll
    for (int nc = 0; nc < 4; ++nc) {
        int n = wn * 64 + nc * 16 + l15;
        b1v[nc] = b1[n];
        w2v[nc] = W2[n];
    }
    const float b2v = b2[0];

    floatx4 acc[4][4];
#pragma unroll
    for (int mr = 0; mr < 4; ++mr)
#pragma unroll
        for (int nc = 0; nc < 4; ++nc)
            acc[mr][nc] = (floatx4){0.f, 0.f, 0.f, 0.f};

    long t = blockIdx.x;
    STAGE(0, t, 0);
    __syncthreads();   // drains stage + prologue loads

    for (; t < (long)ntiles; ) {
        // prefetch this tile's scatter operands into regs (issued BEFORE any
        // stage of this iteration -> later vmcnt waits never drain the stage)
        float vx = 0.f, vy = 0.f, vz = 0.f;
        int node = -1;
        if (tid < BM) {
            long e = t * BM + tid;
            if (e < E) {
                vx = V_st[e * 3 + 0]; vy = V_st[e * 3 + 1]; vz = V_st[e * 3 + 2];
                node = idx_t[e];
            }
        }

        STAGE(1, t, 1);                       // K-half 1 in flight under compute
        compute_half<0>(Abuf[0], bfr, acc, wm, g, l15, q);
        __syncthreads();                      // buf1 ready

        const long tn = t + GRID;
        if (tn < (long)ntiles) STAGE(0, tn, 0);  // next tile's half 0 in flight
        compute_half<1>(Abuf[1], bfr, acc, wm, g, l15, q);

        // ---- epilogue: silu(z+b1) dot W2 over this wave's 64 cols ----
        float part[4][4];
#pragma unroll
        for (int mr = 0; mr < 4; ++mr)
#pragma unroll
            for (int r = 0; r < 4; ++r) {
                float s = 0.f;
#pragma unroll
                for (int nc = 0; nc < 4; ++nc) {
                    float z = acc[mr][nc][r] + b1v[nc];
                    float h = z / (1.f + __expf(-z));
                    s += h * w2v[nc];
                }
                part[mr][r] = s;
            }
#pragma unroll
        for (int mr = 0; mr < 4; ++mr)
#pragma unroll
            for (int nc = 0; nc < 4; ++nc)
                acc[mr][nc] = (floatx4){0.f, 0.f, 0.f, 0.f};

#pragma unroll
        for (int off = 1; off < 16; off <<= 1)
#pragma unroll
            for (int mr = 0; mr < 4; ++mr)
#pragma unroll
                for (int r = 0; r < 4; ++r)
                    part[mr][r] += __shfl_xor(part[mr][r], off, 16);

        if (l15 == 0) {
#pragma unroll
            for (int mr = 0; mr < 4; ++mr)
#pragma unroll
                for (int r = 0; r < 4; ++r)
                    s_red[wn][wm * 64 + mr * 16 + g * 4 + r] = part[mr][r];
        }
        __syncthreads();   // s_red visible; drains STAGE(0,tn)

        // ---- scatter: everything already in registers ----
        if (node >= 0) {
            float s = s_red[0][tid] + s_red[1][tid] + s_red[2][tid] + s_red[3][tid] + b2v;
            atomicAdd(&out[(long)node * 3 + 0], s * vx);
            atomicAdd(&out[(long)node * 3 + 1], s * vy);
            atomicAdd(&out[(long)node * 3 + 2], s * vz);
        }
        t = tn;
        // next iteration's first __syncthreads separates these s_red reads
        // from the next tile's s_red writes
    }
}

extern "C" void kernel_launch(void* const* d_in, const int* in_sizes, int n_in,
                              void* d_out, int out_size, void* d_ws, size_t ws_size,
                              hipStream_t stream) {
    const float* forces = (const float*)d_in[0];
    const float* V_st   = (const float*)d_in[1];
    const float* W1     = (const float*)d_in[2];
    const float* b1     = (const float*)d_in[3];
    const float* W2     = (const float*)d_in[4];
    const float* b2     = (const float*)d_in[5];
    const int*   idx    = (const int*)d_in[6];
    const int E = in_sizes[6];

    u16* W1F = (u16*)d_ws;  // 256*256*2 = 131072 B

    prep_kernel<<<D + 128, 256, 0, stream>>>(W1, W1F, (float*)d_out, out_size);
    head_kernel<<<GRID, NT, 0, stream>>>(forces, V_st, W1F, b1, W2, b2, idx,
                                         (float*)d_out, E);
}

// Round 7
// 329.886 us; speedup vs baseline: 1.1432x; 1.1024x over previous
//
#include <hip/hip_runtime.h>
#include <hip/hip_bf16.h>

typedef __attribute__((ext_vector_type(8))) short short8;
typedef __attribute__((ext_vector_type(4))) float floatx4;
typedef unsigned short u16;

#define D 256
#define BM 128
#define NT 512
#define NBLK 256

__device__ __forceinline__ short f2bf(float f) {
    return __builtin_bit_cast(short, __float2bfloat16(f));
}

// prep: blocks [0,256): W1 fp32 [k][n] -> W1F bf16 MFMA-fragment-major;
//       blocks [256,384): zero d_out.
__global__ void prep_kernel(const float* __restrict__ W1, u16* __restrict__ W1F,
                            float* __restrict__ out, int outn) {
    const int b = blockIdx.x;
    if (b < D) {
        const int k = b, n = threadIdx.x;
        const int k0t = k >> 5, g = (k >> 3) & 3, j = k & 7;
        const int nt = n >> 4, l15 = n & 15;
        W1F[(long)((((k0t << 4) + nt) << 6) + (g << 4) + l15) * 8 + j] = (u16)f2bf(W1[k * D + n]);
    } else {
        int i = (b - D) * 256 + threadIdx.x;
        const int stride = (gridDim.x - D) * 256;
        for (; i < outn; i += stride) out[i] = 0.f;
    }
}

#define GLOAD_LDS(g, l) __builtin_amdgcn_global_load_lds( \
    (const __attribute__((address_space(1))) unsigned int*)(g), \
    (__attribute__((address_space(3))) unsigned int*)(l), 16, 0, 0)

struct R8 { floatx4 f0, f1; };

// Persistent fine-grained pipeline. Per 32-k chunk step:
//   issue reg-loads(chunk+2) | MFMA(chunk) from LDS | cvt+ds_write(chunk+1) | barrier
// A and B both fragment-major in LDS: every ds access is a contiguous 1KiB
// wave transaction (conflict-free, no swizzle). B staged once per block.
__launch_bounds__(NT, 2)
__global__ void head_kernel(const float* __restrict__ forces,
                            const float* __restrict__ V_st,
                            const u16*   __restrict__ W1F,
                            const float* __restrict__ b1,
                            const float* __restrict__ W2,
                            const float* __restrict__ b2,
                            const int*   __restrict__ idx_t,
                            float* __restrict__ out,
                            int E) {
    __shared__ u16 Blds[128 * 512];   // 128 KiB: 128 frags (8 k0t x 16 nt) x 1 KiB
    __shared__ u16 Abuf[2][8 * 512];  // 2 x 8 KiB: 8 frags (row-tiles) x 1 KiB
    __shared__ float s_red[4][BM];    // 2 KiB

    const int tid  = threadIdx.x;
    const int lane = tid & 63;
    const int w    = tid >> 6;        // 0..7
    const int wm   = w >> 2;          // row half 0..1
    const int wn   = w & 3;           // col quarter 0..3
    const int l15  = lane & 15;
    const int g    = lane >> 4;       // 0..3
    const int ntiles = E / BM;        // 6250

    // ---- prologue: B -> LDS (once). Wave w copies frags [w*16, w*16+16). ----
#pragma unroll
    for (int j = 0; j < 16; ++j) {
        int frag = w * 16 + j;
        GLOAD_LDS(W1F + frag * 512 + lane * 8, &Blds[frag * 512]);
    }

    float b1v[4], w2v[4];
#pragma unroll
    for (int nc = 0; nc < 4; ++nc) {
        int n = wn * 64 + nc * 16 + l15;
        b1v[nc] = b1[n];
        w2v[nc] = W2[n];
    }
    const float b2v = b2[0];

    // A staging geometry: thread -> (row=tid>>2, g-chunk=tid&3); writes one
    // 16B slot at frag(row>>4)=w, in-frag lane ((g<<4)|(row&15)). Wave w
    // writes exactly frag w contiguously -> conflict-free.
    const int arow = tid >> 2;
    const int agg  = tid & 3;
    const int aoff = (arow >> 4) * 512 + (((agg << 4) | (arow & 15)) * 8);

    auto ISSUE = [&](int cs) -> R8 {
        long t = (long)blockIdx.x + (long)(cs >> 3) * NBLK;
        if (t >= (long)ntiles) t = 0;   // clamp: harmless read, never computed
        const float* src = forces + (t * BM + arow) * (long)D + (cs & 7) * 32 + agg * 8;
        R8 r;
        r.f0 = *(const floatx4*)src;
        r.f1 = *(const floatx4*)(src + 4);
        return r;
    };
    auto CVTW = [&](int buf, const R8& r) {
        short8 a;
#pragma unroll
        for (int j = 0; j < 4; ++j) { a[j] = f2bf(r.f0[j]); a[4 + j] = f2bf(r.f1[j]); }
        *(short8*)&Abuf[buf][aoff] = a;
    };

    floatx4 acc[4][4];
#pragma unroll
    for (int mr = 0; mr < 4; ++mr)
#pragma unroll
        for (int nc = 0; nc < 4; ++nc)
            acc[mr][nc] = (floatx4){0.f, 0.f, 0.f, 0.f};

    auto COMPUTE = [&](int buf, int k0t) {
        short8 bf[4], af[4];
#pragma unroll
        for (int nc = 0; nc < 4; ++nc)
            bf[nc] = *(const short8*)&Blds[(k0t * 16 + wn * 4 + nc) * 512 + lane * 8];
#pragma unroll
        for (int mr = 0; mr < 4; ++mr)
            af[mr] = *(const short8*)&Abuf[buf][(wm * 4 + mr) * 512 + lane * 8];
#pragma unroll
        for (int mr = 0; mr < 4; ++mr)
#pragma unroll
            for (int nc = 0; nc < 4; ++nc)
                acc[mr][nc] = __builtin_amdgcn_mfma_f32_16x16x32_bf16(
                    af[mr], bf[nc], acc[mr][nc], 0, 0, 0);
    };

    // ---- pipeline prologue: chunk0 in Abuf[0]; chunk1 loads in flight ----
    R8 Ra = ISSUE(0);
    R8 Rb = ISSUE(1);
    CVTW(0, Ra);
    __syncthreads();   // drains B-stage + chunk0 write

    int cs = 0;
    for (long t = blockIdx.x; t < (long)ntiles; t += NBLK) {
        // scatter-operand prefetch (consumed at tile end)
        float vx = 0.f, vy = 0.f, vz = 0.f;
        int node = -1;
        if (tid < BM) {
            long e = t * BM + tid;
            vx = V_st[e * 3 + 0]; vy = V_st[e * 3 + 1]; vz = V_st[e * 3 + 2];
            node = idx_t[e];
        }

        // 8 pipelined k-steps (2 chunks always in flight)
        Ra = ISSUE(cs + 2); COMPUTE(0, 0); CVTW(1, Rb); __syncthreads();
        Rb = ISSUE(cs + 3); COMPUTE(1, 1); CVTW(0, Ra); __syncthreads();
        Ra = ISSUE(cs + 4); COMPUTE(0, 2); CVTW(1, Rb); __syncthreads();
        Rb = ISSUE(cs + 5); COMPUTE(1, 3); CVTW(0, Ra); __syncthreads();
        Ra = ISSUE(cs + 6); COMPUTE(0, 4); CVTW(1, Rb); __syncthreads();
        Rb = ISSUE(cs + 7); COMPUTE(1, 5); CVTW(0, Ra); __syncthreads();
        Ra = ISSUE(cs + 8); COMPUTE(0, 6); CVTW(1, Rb); __syncthreads();
        Rb = ISSUE(cs + 9); COMPUTE(1, 7); CVTW(0, Ra); __syncthreads();
        cs += 8;

        // ---- epilogue: silu(z+b1) dot W2 over this wave's 64 cols ----
        float part[4][4];
#pragma unroll
        for (int mr = 0; mr < 4; ++mr)
#pragma unroll
            for (int r = 0; r < 4; ++r) {
                float sv = 0.f;
#pragma unroll
                for (int nc = 0; nc < 4; ++nc) {
                    float z = acc[mr][nc][r] + b1v[nc];
                    float h = z / (1.f + __expf(-z));
                    sv += h * w2v[nc];
                }
                part[mr][r] = sv;
            }
#pragma unroll
        for (int mr = 0; mr < 4; ++mr)
#pragma unroll
            for (int nc = 0; nc < 4; ++nc)
                acc[mr][nc] = (floatx4){0.f, 0.f, 0.f, 0.f};

#pragma unroll
        for (int off = 1; off < 16; off <<= 1)
#pragma unroll
            for (int mr = 0; mr < 4; ++mr)
#pragma unroll
                for (int r = 0; r < 4; ++r)
                    part[mr][r] += __shfl_xor(part[mr][r], off, 16);

        if (l15 == 0) {
#pragma unroll
            for (int mr = 0; mr < 4; ++mr)
#pragma unroll
                for (int r = 0; r < 4; ++r)
                    s_red[wn][wm * 64 + mr * 16 + g * 4 + r] = part[mr][r];
        }
        __syncthreads();

        if (node >= 0) {
            float sv = s_red[0][tid] + s_red[1][tid] + s_red[2][tid] + s_red[3][tid] + b2v;
            atomicAdd(&out[(long)node * 3 + 0], sv * vx);
            atomicAdd(&out[(long)node * 3 + 1], sv * vy);
            atomicAdd(&out[(long)node * 3 + 2], sv * vz);
        }
        // next s_red write is 8 barriers away -> no extra barrier needed here
    }
}

extern "C" void kernel_launch(void* const* d_in, const int* in_sizes, int n_in,
                              void* d_out, int out_size, void* d_ws, size_t ws_size,
                              hipStream_t stream) {
    const float* forces = (const float*)d_in[0];
    const float* V_st   = (const float*)d_in[1];
    const float* W1     = (const float*)d_in[2];
    const float* b1     = (const float*)d_in[3];
    const float* W2     = (const float*)d_in[4];
    const float* b2     = (const float*)d_in[5];
    const int*   idx    = (const int*)d_in[6];
    const int E = in_sizes[6];

    u16* W1F = (u16*)d_ws;  // 256*256*2 = 131072 B

    prep_kernel<<<D + 128, 256, 0, stream>>>(W1, W1F, (float*)d_out, out_size);
    head_kernel<<<NBLK, NT, 0, stream>>>(forces, V_st, W1F, b1, W2, b2, idx,
                                         (float*)d_out, E);
}

// Round 11
// 282.116 us; speedup vs baseline: 1.3367x; 1.1693x over previous
//
#include <hip/hip_runtime.h>
#include <hip/hip_bf16.h>

typedef __attribute__((ext_vector_type(8))) short short8;
typedef __attribute__((ext_vector_type(4))) float floatx4;
typedef unsigned short u16;

#define D 256
#define BM 64
#define NT 256

__device__ __forceinline__ short f2bf(float f) {
    return __builtin_bit_cast(short, __float2bfloat16(f));
}

// prep: blocks [0,256): W1 fp32 [k][n] -> W1F bf16 MFMA-fragment-major:
// W1F[((k0t*16+nt)*64+lane)*8+j] = W1[k0t*32+(lane>>4)*8+j][nt*16+(lane&15)]
//       blocks [256,384): zero d_out.
__global__ void prep_kernel(const float* __restrict__ W1, u16* __restrict__ W1F,
                            float* __restrict__ out, int outn) {
    const int b = blockIdx.x;
    if (b < D) {
        const int k = b, n = threadIdx.x;
        const int k0t = k >> 5, g = (k >> 3) & 3, j = k & 7;
        const int nt = n >> 4, l15 = n & 15;
        W1F[(long)((((k0t << 4) + nt) << 6) + (g << 4) + l15) * 8 + j] = (u16)f2bf(W1[k * D + n]);
    } else {
        int i = (b - D) * 256 + threadIdx.x;
        const int stride = (gridDim.x - D) * 256;
        for (; i < outn; i += stride) out[i] = 0.f;
    }
}

struct R8 { floatx4 f0, f1; };

// Small-block high-TLP head: 64-edge tile, 4 waves, ~32.5 KiB LDS -> 4 blocks/CU.
// A fragment-major bf16 in LDS (all ds accesses are contiguous 1 KiB wave
// transactions, conflict-free). B per k-step from L2-resident W1F.
__launch_bounds__(NT, 4)
__global__ void head_kernel(const float* __restrict__ forces,
                            const float* __restrict__ V_st,
                            const u16*   __restrict__ W1F,
                            const float* __restrict__ b1,
                            const float* __restrict__ W2,
                            const float* __restrict__ b2,
                            const int*   __restrict__ idx_t,
                            float* __restrict__ out,
                            int E) {
    // frag f = k0t*4 + rt (rt = row>>4); in-frag slot (g*16+l15)*8 shorts
    __shared__ u16 Albs[32 * 512];    // 32 KiB
    __shared__ float s_red[2][BM];    // 512 B

    const int tid  = threadIdx.x;
    const int lane = tid & 63;
    const int w    = tid >> 6;        // 0..3
    const int wm   = w >> 1;          // row half 0..1
    const int wn   = w & 1;           // col half 0..1
    const int l15  = lane & 15;
    const int g    = lane >> 4;       // 0..3

    const long t = blockIdx.x;
    const long row0 = t * BM;

    // ---- scatter-operand prefetch (in flight across the whole block) ----
    float vx = 0.f, vy = 0.f, vz = 0.f;
    int node = -1;
    if (tid < BM) {
        long e = row0 + tid;
        if (e < E) {
            vx = V_st[e * 3 + 0]; vy = V_st[e * 3 + 1]; vz = V_st[e * 3 + 2];
            node = idx_t[e];
        }
    }

    // ---- stage A: thread (arow=tid>>2, agg=tid&3) loads 8 chunks of 8 floats ----
    const int arow = tid >> 2;        // 0..63
    const int agg  = tid & 3;
    long grow = row0 + arow;
    if (grow > (long)E - 1) grow = (long)E - 1;   // never taken when E%64==0
    const float* abase = forces + grow * D + agg * 8;

    R8 r[8];
#pragma unroll
    for (int k0t = 0; k0t < 8; ++k0t) {
        r[k0t].f0 = *(const floatx4*)(abase + k0t * 32);
        r[k0t].f1 = *(const floatx4*)(abase + k0t * 32 + 4);
    }
    const int aslot = ((agg << 4) | (arow & 15)) * 8;
    const int art   = arow >> 4;
#pragma unroll
    for (int k0t = 0; k0t < 8; ++k0t) {
        short8 a;
#pragma unroll
        for (int j = 0; j < 4; ++j) { a[j] = f2bf(r[k0t].f0[j]); a[4 + j] = f2bf(r[k0t].f1[j]); }
        *(short8*)&Albs[(k0t * 4 + art) * 512 + aslot] = a;
    }
    __syncthreads();

    // ---- MFMA: wave tile 32 rows x 128 cols = 2 mr x 8 nc fragments ----
    floatx4 acc[2][8];
#pragma unroll
    for (int mr = 0; mr < 2; ++mr)
#pragma unroll
        for (int nc = 0; nc < 8; ++nc)
            acc[mr][nc] = (floatx4){0.f, 0.f, 0.f, 0.f};

#pragma unroll
    for (int k0t = 0; k0t < 8; ++k0t) {
        short8 bf[8], af[2];
#pragma unroll
        for (int nc = 0; nc < 8; ++nc)
            bf[nc] = *(const short8*)(W1F + (long)((k0t * 16 + wn * 8 + nc) * 64 + lane) * 8);
#pragma unroll
        for (int mr = 0; mr < 2; ++mr)
            af[mr] = *(const short8*)&Albs[(k0t * 4 + wm * 2 + mr) * 512 + lane * 8];
#pragma unroll
        for (int mr = 0; mr < 2; ++mr)
#pragma unroll
            for (int nc = 0; nc < 8; ++nc)
                acc[mr][nc] = __builtin_amdgcn_mfma_f32_16x16x32_bf16(
                    af[mr], bf[nc], acc[mr][nc], 0, 0, 0);
    }

    // ---- epilogue: silu(z+b1) dot W2 over this wave's 128 cols ----
    float b1v[8], w2v[8];
#pragma unroll
    for (int nc = 0; nc < 8; ++nc) {
        int n = wn * 128 + nc * 16 + l15;
        b1v[nc] = b1[n];
        w2v[nc] = W2[n];
    }
    float part[2][4];  // C/D: col=lane&15, row=(lane>>4)*4+reg (m89)
#pragma unroll
    for (int mr = 0; mr < 2; ++mr)
#pragma unroll
        for (int rr = 0; rr < 4; ++rr) {
            float sv = 0.f;
#pragma unroll
            for (int nc = 0; nc < 8; ++nc) {
                float z = acc[mr][nc][rr] + b1v[nc];
                float h = z / (1.f + __expf(-z));
                sv += h * w2v[nc];
            }
            part[mr][rr] = sv;
        }

#pragma unroll
    for (int off = 1; off < 16; off <<= 1)
#pragma unroll
        for (int mr = 0; mr < 2; ++mr)
#pragma unroll
            for (int rr = 0; rr < 4; ++rr)
                part[mr][rr] += __shfl_xor(part[mr][rr], off, 16);

    if (l15 == 0) {
#pragma unroll
        for (int mr = 0; mr < 2; ++mr)
#pragma unroll
            for (int rr = 0; rr < 4; ++rr)
                s_red[wn][wm * 32 + mr * 16 + g * 4 + rr] = part[mr][rr];
    }
    __syncthreads();

    // ---- scalar + scatter (operands already in registers) ----
    if (node >= 0) {
        float sv = s_red[0][tid] + s_red[1][tid] + b2[0];
        atomicAdd(&out[(long)node * 3 + 0], sv * vx);
        atomicAdd(&out[(long)node * 3 + 1], sv * vy);
        atomicAdd(&out[(long)node * 3 + 2], sv * vz);
    }
}

extern "C" void kernel_launch(void* const* d_in, const int* in_sizes, int n_in,
                              void* d_out, int out_size, void* d_ws, size_t ws_size,
                              hipStream_t stream) {
    const float* forces = (const float*)d_in[0];
    const float* V_st   = (const float*)d_in[1];
    const float* W1     = (const float*)d_in[2];
    const float* b1     = (const float*)d_in[3];
    const float* W2     = (const float*)d_in[4];
    const float* b2     = (const float*)d_in[5];
    const int*   idx    = (const int*)d_in[6];
    const int E = in_sizes[6];

    u16* W1F = (u16*)d_ws;  // 256*256*2 = 131072 B

    prep_kernel<<<D + 128, 256, 0, stream>>>(W1, W1F, (float*)d_out, out_size);
    const int grid = (E + BM - 1) / BM;
    head_kernel<<<grid, NT, 0, stream>>>(forces, V_st, W1F, b1, W2, b2, idx,
                                         (float*)d_out, E);
}